// Round 2
// baseline (258.460 us; speedup 1.0000x reference)
//
#include <hip/hip_runtime.h>
#include <hip/hip_cooperative_groups.h>

namespace cg = cooperative_groups;

// Problem constants (fixed by reference setup_inputs)
#define NUMB 32     // num
#define LL   128    // num_top*cobj
#define POOL 1200   // cobj*bag
#define BAG  300
#define DD   256    // feature dim
#define HH   256    // relation hidden
#define NS   (NUMB*32*32)   // 32768 scores

using bf16x8 = __bf16    __attribute__((ext_vector_type(8)));
using f32x4  = float     __attribute__((ext_vector_type(4)));
using fp16x2 = __fp16    __attribute__((ext_vector_type(2)));  // cvt_pkrtz result
using h16x2  = _Float16  __attribute__((ext_vector_type(2)));  // fdot2 operand
using h16x8  = _Float16  __attribute__((ext_vector_type(8)));

typedef const __attribute__((address_space(1))) unsigned int* gas_t;
typedef       __attribute__((address_space(3))) unsigned int* las_t;

static __device__ __forceinline__ unsigned short f2bf(float x) {
    unsigned u = __float_as_uint(x);
    return (unsigned short)((u + 0x7FFFu + ((u >> 16) & 1u)) >> 16);  // RNE
}

static __device__ __forceinline__ float pkh(float a, float b) {
    fp16x2 p = __builtin_amdgcn_cvt_pkrtz(a, b);
    return __builtin_bit_cast(float, p);
}

// pack two f32 -> two bf16 in one instr (lo = a, hi = b)
static __device__ __forceinline__ unsigned int pkbf(float a, float b) {
    unsigned int r;
    asm("v_cvt_pk_bf16_f32 %0, %1, %2" : "=v"(r) : "v"(a), "v"(b));
    return r;
}

// ===========================================================================
// FUSED cooperative kernel: prep + gemm + pair with 2 grid syncs.
//  grid = 512 x 256thr, 64KB LDS -> exactly 2 blocks/CU co-resident (512).
//  Phase 0: blocks 0..31 do W-transpose prep (T aliased on As) while ALL
//           blocks do the B gather/bf16-convert staging (prep hides).
//  Phase 1: A staging (global_load_lds from WtP, pre-swizzled) + K-loop
//           (16x16x32 bf16 MFMA, 2x2 wave tile) + Hh fp16 epilogue.
//  Phase 2: pairwise relu-reduce (s0/s1 aliased on As; w2s/sred on Bs).
//  XCD-chunk swizzle (b0&7)*64+(b0>>3) applied to both phase decodes.
// ===========================================================================
__global__ __launch_bounds__(256) void k_fused(
    const float* __restrict__ fea,
    const int*   __restrict__ ind0,
    const int*   __restrict__ ind1,
    const float* __restrict__ W1a,
    const float* __restrict__ W1b,
    const float* __restrict__ b1,
    const float* __restrict__ W2,
    const float* __restrict__ b2,
    unsigned short* __restrict__ WtP,
    unsigned short* __restrict__ Hh,
    float*       __restrict__ out)
{
    __shared__ unsigned short As[64 * 256] __attribute__((aligned(16))); // 32KB
    __shared__ unsigned short Bs[64 * 256] __attribute__((aligned(16))); // 32KB

    const int b0 = blockIdx.x;
    const int t = threadIdx.x, w = t >> 6, lane = t & 63;

    // gemm decode (needed in phases 0 and 1)
    const int bg = (b0 & 7) * 64 + (b0 >> 3);    // XCD-chunk swizzle (512 = 8*64)
    const int ht = bg & 3, rt = bg >> 2;
    const int side = rt >> 6;
    const int R0 = rt * 64;

    // ---- phase 0a: prep (blocks 0..31); T[16][257] aliased onto As ------
    if (b0 < 32) {
        const int pside = b0 >> 4, kc = b0 & 15;   // k-chunk of 16
        const float* W = pside ? W1b : W1a;        // [k][h] row-major
        float (*T)[257] = (float (*)[257])(void*)As;
        const int row = t >> 4, c = t & 15;
#pragma unroll
        for (int i = 0; i < 4; ++i) {
            int col4 = c + i * 16;
            float4 v = *(const float4*)(W + (size_t)(kc * 16 + row) * HH + col4 * 4);
            T[row][col4 * 4 + 0] = v.x; T[row][col4 * 4 + 1] = v.y;
            T[row][col4 * 4 + 2] = v.z; T[row][col4 * 4 + 3] = v.w;
        }
        __syncthreads();
        const int pht = t >> 6, nn = t & 63;
#pragma unroll
        for (int j = 0; j < 2; ++j) {
            unsigned short tmp[8] __attribute__((aligned(16)));
#pragma unroll
            for (int e = 0; e < 8; ++e) tmp[e] = f2bf(T[j * 8 + e][t]);
            int U = kc * 2 + j;
            int pos = U ^ (nn & 7);
            size_t unit = ((size_t)((pside * 4 + pht) * 64 + nn)) * 32 + pos;
            *(float4*)(WtP + unit * 8) = *(float4*)tmp;
        }
        __syncthreads();   // done with As-as-T before leaving prep
    }

    // ---- phase 0b: B staging (all blocks): gather fp32, cvt_pk, swz write --
    {
        const int lr = t >> 2;               // local row 0..63
        const int g = R0 + lr;
        const int rs = g & 4095, n_ = rs >> 7, a_ = rs & 127;
        const int id = (side ? ind1 : ind0)[n_ * LL + a_] + BAG * (a_ & 3);
        const float* arow = fea + (size_t)((n_ * 2 + side) * POOL + id) * DD;
        const int sw = lr & 7;
#pragma unroll
        for (int j0 = 0; j0 < 8; ++j0) {
            int u = j0 * 4 + (t & 3);        // 16B-unit 0..31
            float4 v0 = *(const float4*)(arow + u * 8);
            float4 v1 = *(const float4*)(arow + u * 8 + 4);
            unsigned int tmp[4] __attribute__((aligned(16)));
            tmp[0] = pkbf(v0.x, v0.y);
            tmp[1] = pkbf(v0.z, v0.w);
            tmp[2] = pkbf(v1.x, v1.y);
            tmp[3] = pkbf(v1.z, v1.w);
            int pos = u ^ sw;
            *(f32x4*)&Bs[lr * 256 + pos * 8] = *(const f32x4*)tmp;
        }
    }
    __syncthreads();
    cg::this_grid().sync();                  // WtP visible everywhere

    // ---- phase 1: A staging (async, layout pre-swizzled in WtP) ----------
    const unsigned short* Wbase = WtP + ((size_t)(side * 4 + ht)) * 64 * 256;
#pragma unroll
    for (int i = 0; i < 8; ++i) {
        int chunk = w * 8 + i;               // 32 chunks of 1KB
        __builtin_amdgcn_global_load_lds(
            (gas_t)(const void*)(Wbase + chunk * 512 + lane * 8),
            (las_t)(void*)(As + chunk * 512),
            16, 0, 0);
    }
    __syncthreads();   // drains global_load_lds (vmcnt)

    // K loop: 8 steps of K=32, pure LDS->MFMA, 2x2 wave tile
    const int l15 = lane & 15, q = lane >> 4;
    const int wh = w >> 1, wr = w & 1;
    f32x4 acc[2][2] = {};
#pragma unroll
    for (int kk = 0; kk < 8; ++kk) {
        const int u = kk * 4 + q;
        bf16x8 af[2], bfv[2];
#pragma unroll
        for (int a = 0; a < 2; ++a) {
            int hr = wh * 32 + a * 16 + l15;
            af[a] = *(const bf16x8*)&As[hr * 256 + (u ^ (hr & 7)) * 8];
        }
#pragma unroll
        for (int r = 0; r < 2; ++r) {
            int rr = wr * 32 + r * 16 + l15;
            bfv[r] = *(const bf16x8*)&Bs[rr * 256 + (u ^ (rr & 7)) * 8];
        }
#pragma unroll
        for (int a = 0; a < 2; ++a)
#pragma unroll
            for (int r = 0; r < 2; ++r)
                acc[a][r] = __builtin_amdgcn_mfma_f32_16x16x32_bf16(af[a], bfv[r], acc[a][r], 0, 0, 0);
    }

    // epilogue: +b1 (side 0), fp32 -> fp16, 8B stores into Hh[row][h]
    {
        const int hq = ht * 64 + wh * 32 + q * 4;
        float4 bias[2];
        bias[0] = make_float4(0.f, 0.f, 0.f, 0.f);
        bias[1] = bias[0];
        if (side == 0) {
            bias[0] = *(const float4*)(b1 + hq);
            bias[1] = *(const float4*)(b1 + hq + 16);
        }
#pragma unroll
        for (int a = 0; a < 2; ++a)
#pragma unroll
        for (int r = 0; r < 2; ++r) {
            int frow = R0 + wr * 32 + r * 16 + l15;
            float2 pk;
            pk.x = pkh(acc[a][r][0] + bias[a].x, acc[a][r][1] + bias[a].y);
            pk.y = pkh(acc[a][r][2] + bias[a].z, acc[a][r][3] + bias[a].w);
            *(float2*)&Hh[(size_t)frow * HH + hq + a * 16] = pk;
        }
    }
    cg::this_grid().sync();                  // Hh visible everywhere

    // ---- phase 2: pair. s0/s1 alias As; w2s/sred alias Bs -----------------
    unsigned short* s0  = As;                // 16KB
    unsigned short* s1  = As + 32 * 256;     // 16KB
    unsigned short* w2s = Bs;                // 512B
    float*          sred = (float*)(void*)(Bs + 256); // 1KB

    int bp = (b0 & 7) * 64 + (b0 >> 3);
    const int jt = bp & 3;  bp >>= 2;
    const int it = bp & 3;  bp >>= 2;
    const int n  = bp;

    const size_t base0 = ((size_t)(n * LL) + it * 32) * HH;
    const size_t base1 = ((size_t)(NUMB * LL + n * LL) + jt * 32) * HH;

    // async staging: wave w stages rows w*8..w*8+7 of both tiles.
    // LDS slot (row,pos) receives global h-unit f = pos ^ ((row>>2)&7).
    {
        const int pos = lane & 31, rhalf = lane >> 5;
#pragma unroll
        for (int i = 0; i < 4; ++i) {
            int rowbase = w * 8 + i * 2;
            int row = rowbase + rhalf;
            int f = pos ^ ((row >> 2) & 7);
            __builtin_amdgcn_global_load_lds(
                (gas_t)(const void*)(Hh + base0 + (size_t)row * HH + f * 8),
                (las_t)(void*)(s0 + rowbase * 256), 16, 0, 0);
            __builtin_amdgcn_global_load_lds(
                (gas_t)(const void*)(Hh + base1 + (size_t)row * HH + f * 8),
                (las_t)(void*)(s1 + rowbase * 256), 16, 0, 0);
        }
    }
    if (t < 64) {
        float4 v = *(const float4*)(W2 + t * 4);
        float2 pk;
        pk.x = pkh(v.x, v.y);
        pk.y = pkh(v.z, v.w);
        *(float2*)&w2s[t * 4] = pk;
    }
    __syncthreads();

    const int il = (t >> 3) & 7, jl = t & 7;
    float acc2[4][4] = {{0.f,0.f,0.f,0.f},{0.f,0.f,0.f,0.f},
                        {0.f,0.f,0.f,0.f},{0.f,0.f,0.f,0.f}};

#pragma unroll
    for (int f = 0; f < 8; ++f) {
        h16x8 wv = *(const h16x8*)&w2s[(w * 8 + f) * 8];   // wave-uniform
        const h16x2* wp = (const h16x2*)&wv;
        h16x8 av[4], bv[4];
#pragma unroll
        for (int r = 0; r < 4; ++r)
            av[r] = *(const h16x8*)&s0[(il * 4 + r) * 256 + (w * 8 + (f ^ il)) * 8];
#pragma unroll
        for (int s = 0; s < 4; ++s)
            bv[s] = *(const h16x8*)&s1[(jl * 4 + s) * 256 + (w * 8 + (f ^ jl)) * 8];
        const h16x8 zero = {0, 0, 0, 0, 0, 0, 0, 0};
#pragma unroll
        for (int r = 0; r < 4; ++r)
#pragma unroll
            for (int s = 0; s < 4; ++s) {
                h16x8 sum = av[r] + bv[s];                  // v_pk_add_f16 x4
                sum = __builtin_elementwise_max(sum, zero); // v_pk_max_f16 x4
                const h16x2* sp = (const h16x2*)&sum;
#pragma unroll
                for (int u = 0; u < 4; ++u)
                    acc2[r][s] = __builtin_amdgcn_fdot2(sp[u], wp[u], acc2[r][s], false);
            }
    }

    float total = 0.f;
#pragma unroll
    for (int r = 0; r < 4; ++r)
#pragma unroll
        for (int s = 0; s < 4; ++s) total += acc2[r][s];

    sred[t] = total;
    __syncthreads();

    if (t < 64) {
        float sum = sred[t] + sred[t + 64] + sred[t + 128] + sred[t + 192]
                  + 16.0f * b2[0];
        int i = it * 8 + (t >> 3);
        int j = jt * 8 + (t & 7);
        int p = n * 1024 + i * 32 + j;
        out[p] = sum;
        *(float2*)(out + NS + 2 * p) = make_float2((float)i, (float)j);
    }
}

// ===========================================================================
// Fallback 3-kernel path (used only if cooperative launch is rejected).
// ===========================================================================
__global__ __launch_bounds__(256) void k_prep(
    const float* __restrict__ W1a, const float* __restrict__ W1b,
    unsigned short* __restrict__ WtP)
{
    const int blk = blockIdx.x, t = threadIdx.x;
    const int side = blk >> 4, kc = blk & 15;
    const float* W = side ? W1b : W1a;
    __shared__ float T[16][257];
    const int row = t >> 4, c = t & 15;
#pragma unroll
    for (int i = 0; i < 4; ++i) {
        int col4 = c + i * 16;
        float4 v = *(const float4*)(W + (size_t)(kc * 16 + row) * HH + col4 * 4);
        T[row][col4 * 4 + 0] = v.x; T[row][col4 * 4 + 1] = v.y;
        T[row][col4 * 4 + 2] = v.z; T[row][col4 * 4 + 3] = v.w;
    }
    __syncthreads();
    const int ht = t >> 6, nn = t & 63;
#pragma unroll
    for (int j = 0; j < 2; ++j) {
        unsigned short tmp[8] __attribute__((aligned(16)));
#pragma unroll
        for (int e = 0; e < 8; ++e) tmp[e] = f2bf(T[j * 8 + e][t]);
        int U = kc * 2 + j;
        int pos = U ^ (nn & 7);
        size_t unit = ((size_t)((side * 4 + ht) * 64 + nn)) * 32 + pos;
        *(float4*)(WtP + unit * 8) = *(float4*)tmp;
    }
}

__global__ __launch_bounds__(256) void k_gemm(
    const float* __restrict__ fea,
    const int*   __restrict__ ind0,
    const int*   __restrict__ ind1,
    const float* __restrict__ b1,
    const unsigned short* __restrict__ WtP,
    unsigned short* __restrict__ Hh)
{
    __shared__ unsigned short As[64 * 256] __attribute__((aligned(16)));
    __shared__ unsigned short Bs[64 * 256] __attribute__((aligned(16)));

    const int b0 = blockIdx.x;
    const int b = (b0 & 7) * 64 + (b0 >> 3);
    const int ht = b & 3, rt = b >> 2;
    const int side = rt >> 6;
    const int R0 = rt * 64;
    const int t = threadIdx.x, w = t >> 6, lane = t & 63;

    const unsigned short* Wbase = WtP + ((size_t)(side * 4 + ht)) * 64 * 256;
#pragma unroll
    for (int i = 0; i < 8; ++i) {
        int chunk = w * 8 + i;
        __builtin_amdgcn_global_load_lds(
            (gas_t)(const void*)(Wbase + chunk * 512 + lane * 8),
            (las_t)(void*)(As + chunk * 512),
            16, 0, 0);
    }
    {
        const int lr = t >> 2;
        const int g = R0 + lr;
        const int rs = g & 4095, n_ = rs >> 7, a_ = rs & 127;
        const int id = (side ? ind1 : ind0)[n_ * LL + a_] + BAG * (a_ & 3);
        const float* arow = fea + (size_t)((n_ * 2 + side) * POOL + id) * DD;
        const int sw = lr & 7;
#pragma unroll
        for (int j0 = 0; j0 < 8; ++j0) {
            int u = j0 * 4 + (t & 3);
            float4 v0 = *(const float4*)(arow + u * 8);
            float4 v1 = *(const float4*)(arow + u * 8 + 4);
            unsigned int tmp[4] __attribute__((aligned(16)));
            tmp[0] = pkbf(v0.x, v0.y);
            tmp[1] = pkbf(v0.z, v0.w);
            tmp[2] = pkbf(v1.x, v1.y);
            tmp[3] = pkbf(v1.z, v1.w);
            int pos = u ^ sw;
            *(f32x4*)&Bs[lr * 256 + pos * 8] = *(const f32x4*)tmp;
        }
    }
    __syncthreads();

    const int l15 = lane & 15, q = lane >> 4;
    const int wh = w >> 1, wr = w & 1;
    f32x4 acc[2][2] = {};
#pragma unroll
    for (int kk = 0; kk < 8; ++kk) {
        const int u = kk * 4 + q;
        bf16x8 af[2], bfv[2];
#pragma unroll
        for (int a = 0; a < 2; ++a) {
            int hr = wh * 32 + a * 16 + l15;
            af[a] = *(const bf16x8*)&As[hr * 256 + (u ^ (hr & 7)) * 8];
        }
#pragma unroll
        for (int r = 0; r < 2; ++r) {
            int rr = wr * 32 + r * 16 + l15;
            bfv[r] = *(const bf16x8*)&Bs[rr * 256 + (u ^ (rr & 7)) * 8];
        }
#pragma unroll
        for (int a = 0; a < 2; ++a)
#pragma unroll
            for (int r = 0; r < 2; ++r)
                acc[a][r] = __builtin_amdgcn_mfma_f32_16x16x32_bf16(af[a], bfv[r], acc[a][r], 0, 0, 0);
    }

    const int hq = ht * 64 + wh * 32 + q * 4;
    float4 bias[2];
    bias[0] = make_float4(0.f, 0.f, 0.f, 0.f);
    bias[1] = bias[0];
    if (side == 0) {
        bias[0] = *(const float4*)(b1 + hq);
        bias[1] = *(const float4*)(b1 + hq + 16);
    }
#pragma unroll
    for (int a = 0; a < 2; ++a)
#pragma unroll
    for (int r = 0; r < 2; ++r) {
        int frow = R0 + wr * 32 + r * 16 + l15;
        float2 pk;
        pk.x = pkh(acc[a][r][0] + bias[a].x, acc[a][r][1] + bias[a].y);
        pk.y = pkh(acc[a][r][2] + bias[a].z, acc[a][r][3] + bias[a].w);
        *(float2*)&Hh[(size_t)frow * HH + hq + a * 16] = pk;
    }
}

__global__ __launch_bounds__(256) void k_pair(
    const unsigned short* __restrict__ Hh,
    const float* __restrict__ W2,
    const float* __restrict__ b2,
    float*       __restrict__ out)
{
    __shared__ unsigned short s0[32 * 256] __attribute__((aligned(16)));
    __shared__ unsigned short s1[32 * 256] __attribute__((aligned(16)));
    __shared__ unsigned short w2s[256]     __attribute__((aligned(16)));
    __shared__ float sred[256];

    const int b0 = blockIdx.x;
    int b = (b0 & 7) * 64 + (b0 >> 3);
    const int jt = b & 3;  b >>= 2;
    const int it = b & 3;  b >>= 2;
    const int n  = b;
    const int t = threadIdx.x, w = t >> 6, lane = t & 63;

    const size_t base0 = ((size_t)(n * LL) + it * 32) * HH;
    const size_t base1 = ((size_t)(NUMB * LL + n * LL) + jt * 32) * HH;

    {
        const int pos = lane & 31, rhalf = lane >> 5;
#pragma unroll
        for (int i = 0; i < 4; ++i) {
            int rowbase = w * 8 + i * 2;
            int row = rowbase + rhalf;
            int f = pos ^ ((row >> 2) & 7);
            __builtin_amdgcn_global_load_lds(
                (gas_t)(const void*)(Hh + base0 + (size_t)row * HH + f * 8),
                (las_t)(void*)(s0 + rowbase * 256), 16, 0, 0);
            __builtin_amdgcn_global_load_lds(
                (gas_t)(const void*)(Hh + base1 + (size_t)row * HH + f * 8),
                (las_t)(void*)(s1 + rowbase * 256), 16, 0, 0);
        }
    }
    if (t < 64) {
        float4 v = *(const float4*)(W2 + t * 4);
        float2 pk;
        pk.x = pkh(v.x, v.y);
        pk.y = pkh(v.z, v.w);
        *(float2*)&w2s[t * 4] = pk;
    }
    __syncthreads();

    const int il = (t >> 3) & 7, jl = t & 7;
    float acc[4][4] = {{0.f,0.f,0.f,0.f},{0.f,0.f,0.f,0.f},
                       {0.f,0.f,0.f,0.f},{0.f,0.f,0.f,0.f}};

#pragma unroll
    for (int f = 0; f < 8; ++f) {
        h16x8 wv = *(const h16x8*)&w2s[(w * 8 + f) * 8];
        const h16x2* wp = (const h16x2*)&wv;
        h16x8 av[4], bv[4];
#pragma unroll
        for (int r = 0; r < 4; ++r)
            av[r] = *(const h16x8*)&s0[(il * 4 + r) * 256 + (w * 8 + (f ^ il)) * 8];
#pragma unroll
        for (int s = 0; s < 4; ++s)
            bv[s] = *(const h16x8*)&s1[(jl * 4 + s) * 256 + (w * 8 + (f ^ jl)) * 8];
        const h16x8 zero = {0, 0, 0, 0, 0, 0, 0, 0};
#pragma unroll
        for (int r = 0; r < 4; ++r)
#pragma unroll
            for (int s = 0; s < 4; ++s) {
                h16x8 sum = av[r] + bv[s];
                sum = __builtin_elementwise_max(sum, zero);
                const h16x2* sp = (const h16x2*)&sum;
#pragma unroll
                for (int u = 0; u < 4; ++u)
                    acc[r][s] = __builtin_amdgcn_fdot2(sp[u], wp[u], acc[r][s], false);
            }
    }

    float total = 0.f;
#pragma unroll
    for (int r = 0; r < 4; ++r)
#pragma unroll
        for (int s = 0; s < 4; ++s) total += acc[r][s];

    sred[t] = total;
    __syncthreads();

    if (t < 64) {
        float sum = sred[t] + sred[t + 64] + sred[t + 128] + sred[t + 192]
                  + 16.0f * b2[0];
        int i = it * 8 + (t >> 3);
        int j = jt * 8 + (t & 7);
        int p = n * 1024 + i * 32 + j;
        out[p] = sum;
        *(float2*)(out + NS + 2 * p) = make_float2((float)i, (float)j);
    }
}

// ---------------------------------------------------------------------------
extern "C" void kernel_launch(void* const* d_in, const int* in_sizes, int n_in,
                              void* d_out, int out_size, void* d_ws, size_t ws_size,
                              hipStream_t stream)
{
    const float* fea  = (const float*)d_in[0];
    const int*   ind0 = (const int*)  d_in[1];
    const int*   ind1 = (const int*)  d_in[2];
    // d_in[3] = k (scalar 8, compile-time constant here)
    const float* W1a  = (const float*)d_in[4];
    const float* W1b  = (const float*)d_in[5];
    const float* b1   = (const float*)d_in[6];
    const float* W2   = (const float*)d_in[7];
    const float* b2   = (const float*)d_in[8];
    float* out = (float*)d_out;

    unsigned short* WtP = (unsigned short*)d_ws;                 // 256KB bf16
    unsigned short* Hh  = (unsigned short*)((char*)d_ws + 512 * 1024); // 4MB fp16

    void* kargs[] = {
        (void*)&fea, (void*)&ind0, (void*)&ind1,
        (void*)&W1a, (void*)&W1b, (void*)&b1,
        (void*)&W2,  (void*)&b2,
        (void*)&WtP, (void*)&Hh, (void*)&out
    };
    hipError_t e = hipLaunchCooperativeKernel(k_fused, dim3(512), dim3(256),
                                              kargs, 0u, stream);
    if (e != hipSuccess) {
        // Fallback: proven 3-kernel path (identical math).
        hipLaunchKernelGGL(k_prep, dim3(32), dim3(256), 0, stream,
                           W1a, W1b, WtP);
        hipLaunchKernelGGL(k_gemm, dim3(512), dim3(256), 0, stream,
                           fea, ind0, ind1, b1, WtP, Hh);
        hipLaunchKernelGGL(k_pair, dim3(512), dim3(256), 0, stream,
                           Hh, W2, b2, out);
    }
}

// Round 3
// 199.575 us; speedup vs baseline: 1.2950x; 1.2950x over previous
//
#include <hip/hip_runtime.h>

// Problem constants (fixed by reference setup_inputs)
#define NUMB 32     // num
#define LL   128    // num_top*cobj
#define POOL 1200   // cobj*bag
#define BAG  300
#define DD   256    // feature dim
#define HH   256    // relation hidden
#define NS   (NUMB*32*32)   // 32768 scores
#define NBLK 512u

using bf16x8 = __bf16    __attribute__((ext_vector_type(8)));
using f32x4  = float     __attribute__((ext_vector_type(4)));
using fp16x2 = __fp16    __attribute__((ext_vector_type(2)));  // cvt_pkrtz result
using h16x2  = _Float16  __attribute__((ext_vector_type(2)));  // fdot2 operand
using h16x8  = _Float16  __attribute__((ext_vector_type(8)));

typedef const __attribute__((address_space(1))) unsigned int* gas_t;
typedef       __attribute__((address_space(3))) unsigned int* las_t;

static __device__ __forceinline__ unsigned short f2bf(float x) {
    unsigned u = __float_as_uint(x);
    return (unsigned short)((u + 0x7FFFu + ((u >> 16) & 1u)) >> 16);  // RNE
}

static __device__ __forceinline__ float pkh(float a, float b) {
    fp16x2 p = __builtin_amdgcn_cvt_pkrtz(a, b);
    return __builtin_bit_cast(float, p);
}

// pack two f32 -> two bf16 in one instr (lo = a, hi = b)
static __device__ __forceinline__ unsigned int pkbf(float a, float b) {
    unsigned int r;
    asm("v_cvt_pk_bf16_f32 %0, %1, %2" : "=v"(r) : "v"(a), "v"(b));
    return r;
}

// Hand-rolled grid barrier (cooperative launch guarantees co-residency).
// Leader: release-RMW arrive (flushes XCD L2 to coherence point), relaxed
// spin to NBLK, acquire fence (invalidates L1/L2). ~2-5us vs cg::sync ~50us.
// cnt must be zeroed before the dispatch (done by k_prep).
static __device__ __forceinline__ void gridbar(unsigned* cnt) {
    __syncthreads();   // compiler drains vmcnt/lgkmcnt before s_barrier
    if (threadIdx.x == 0) {
        __hip_atomic_fetch_add(cnt, 1u, __ATOMIC_RELEASE, __HIP_MEMORY_SCOPE_AGENT);
        unsigned v;
        do { v = __hip_atomic_load(cnt, __ATOMIC_RELAXED, __HIP_MEMORY_SCOPE_AGENT); }
        while (v < NBLK);
        __builtin_amdgcn_fence(__ATOMIC_ACQUIRE, "agent");
    }
    __syncthreads();
}

// ---------------------------------------------------------------------------
// K0: W transpose+convert -> WtP bf16, pre-swizzled (32 blocks); also zeroes
//     the grid-barrier counter for the fused kernel that follows.
// ---------------------------------------------------------------------------
__global__ __launch_bounds__(256) void k_prep(
    const float* __restrict__ W1a, const float* __restrict__ W1b,
    unsigned short* __restrict__ WtP, unsigned* __restrict__ cnt)
{
    const int blk = blockIdx.x, t = threadIdx.x;
    if (blk == 0 && t == 0)
        __hip_atomic_store(cnt, 0u, __ATOMIC_RELAXED, __HIP_MEMORY_SCOPE_AGENT);
    const int side = blk >> 4, kc = blk & 15;   // k-chunk of 16
    const float* W = side ? W1b : W1a;          // [k][h] row-major
    __shared__ float T[16][257];
    const int row = t >> 4, c = t & 15;
#pragma unroll
    for (int i = 0; i < 4; ++i) {
        int col4 = c + i * 16;
        float4 v = *(const float4*)(W + (size_t)(kc * 16 + row) * HH + col4 * 4);
        T[row][col4 * 4 + 0] = v.x; T[row][col4 * 4 + 1] = v.y;
        T[row][col4 * 4 + 2] = v.z; T[row][col4 * 4 + 3] = v.w;
    }
    __syncthreads();
    const int ht = t >> 6, nn = t & 63;
#pragma unroll
    for (int j = 0; j < 2; ++j) {
        unsigned short tmp[8] __attribute__((aligned(16)));
#pragma unroll
        for (int e = 0; e < 8; ++e) tmp[e] = f2bf(T[j * 8 + e][t]);
        int U = kc * 2 + j;
        int pos = U ^ (nn & 7);
        size_t unit = ((size_t)((side * 4 + ht) * 64 + nn)) * 32 + pos;
        *(float4*)(WtP + unit * 8) = *(float4*)tmp;
    }
}

// ===========================================================================
// FUSED gemm+pair: one cooperative dispatch, ONE custom grid barrier.
//  Phase A == k_gemm body (B gather/cvt staging, A async from WtP, K-loop,
//  Hh fp16 epilogue).  gridbar.  Phase B == k_pair body (s0/s1 alias As,
//  w2s/sred alias Bs).  64KB LDS -> exactly 2 blocks/CU (grid 512).
// ===========================================================================
__global__ __launch_bounds__(256) void k_fused(
    const float* __restrict__ fea,
    const int*   __restrict__ ind0,
    const int*   __restrict__ ind1,
    const float* __restrict__ b1,
    const float* __restrict__ W2,
    const float* __restrict__ b2,
    const unsigned short* __restrict__ WtP,
    unsigned short* __restrict__ Hh,
    float*       __restrict__ out,
    unsigned*    __restrict__ cnt)
{
    __shared__ unsigned short As[64 * 256] __attribute__((aligned(16))); // 32KB
    __shared__ unsigned short Bs[64 * 256] __attribute__((aligned(16))); // 32KB

    const int b0 = blockIdx.x;
    const int t = threadIdx.x, w = t >> 6, lane = t & 63;

    // ---- phase A: gemm --------------------------------------------------
    {
        const int bg = (b0 & 7) * 64 + (b0 >> 3);  // XCD-chunk swizzle
        const int ht = bg & 3, rt = bg >> 2;
        const int side = rt >> 6;
        const int R0 = rt * 64;

        // A staging: async global->LDS, layout pre-swizzled in WtP
        const unsigned short* Wbase = WtP + ((size_t)(side * 4 + ht)) * 64 * 256;
#pragma unroll
        for (int i = 0; i < 8; ++i) {
            int chunk = w * 8 + i;               // 32 chunks of 1KB
            __builtin_amdgcn_global_load_lds(
                (gas_t)(const void*)(Wbase + chunk * 512 + lane * 8),
                (las_t)(void*)(As + chunk * 512),
                16, 0, 0);
        }

        // B staging: gather fp32 row, cvt_pk bf16, swizzled ds_write_b128
        {
            const int lr = t >> 2;               // local row 0..63
            const int g = R0 + lr;
            const int rs = g & 4095, n_ = rs >> 7, a_ = rs & 127;
            const int id = (side ? ind1 : ind0)[n_ * LL + a_] + BAG * (a_ & 3);
            const float* arow = fea + (size_t)((n_ * 2 + side) * POOL + id) * DD;
            const int sw = lr & 7;
#pragma unroll
            for (int j0 = 0; j0 < 8; ++j0) {
                int u = j0 * 4 + (t & 3);        // 16B-unit 0..31
                float4 v0 = *(const float4*)(arow + u * 8);
                float4 v1 = *(const float4*)(arow + u * 8 + 4);
                unsigned int tmp[4] __attribute__((aligned(16)));
                tmp[0] = pkbf(v0.x, v0.y);
                tmp[1] = pkbf(v0.z, v0.w);
                tmp[2] = pkbf(v1.x, v1.y);
                tmp[3] = pkbf(v1.z, v1.w);
                int pos = u ^ sw;
                *(f32x4*)&Bs[lr * 256 + pos * 8] = *(const f32x4*)tmp;
            }
        }
        __syncthreads();   // drains global_load_lds (vmcnt) + ds_writes

        // K loop: 8 steps of K=32, pure LDS->MFMA, 2x2 wave tile
        const int l15 = lane & 15, q = lane >> 4;
        const int wh = w >> 1, wr = w & 1;
        f32x4 acc[2][2] = {};
#pragma unroll
        for (int kk = 0; kk < 8; ++kk) {
            const int u = kk * 4 + q;
            bf16x8 af[2], bfv[2];
#pragma unroll
            for (int a = 0; a < 2; ++a) {
                int hr = wh * 32 + a * 16 + l15;
                af[a] = *(const bf16x8*)&As[hr * 256 + (u ^ (hr & 7)) * 8];
            }
#pragma unroll
            for (int r = 0; r < 2; ++r) {
                int rr = wr * 32 + r * 16 + l15;
                bfv[r] = *(const bf16x8*)&Bs[rr * 256 + (u ^ (rr & 7)) * 8];
            }
#pragma unroll
            for (int a = 0; a < 2; ++a)
#pragma unroll
                for (int r = 0; r < 2; ++r)
                    acc[a][r] = __builtin_amdgcn_mfma_f32_16x16x32_bf16(af[a], bfv[r], acc[a][r], 0, 0, 0);
        }

        // epilogue: +b1 (side 0), fp32 -> fp16, 8B stores into Hh[row][h]
        const int hq = ht * 64 + wh * 32 + q * 4;
        float4 bias[2];
        bias[0] = make_float4(0.f, 0.f, 0.f, 0.f);
        bias[1] = bias[0];
        if (side == 0) {
            bias[0] = *(const float4*)(b1 + hq);
            bias[1] = *(const float4*)(b1 + hq + 16);
        }
#pragma unroll
        for (int a = 0; a < 2; ++a)
#pragma unroll
        for (int r = 0; r < 2; ++r) {
            int frow = R0 + wr * 32 + r * 16 + l15;
            float2 pk;
            pk.x = pkh(acc[a][r][0] + bias[a].x, acc[a][r][1] + bias[a].y);
            pk.y = pkh(acc[a][r][2] + bias[a].z, acc[a][r][3] + bias[a].w);
            *(float2*)&Hh[(size_t)frow * HH + hq + a * 16] = pk;
        }
    }

    gridbar(cnt);                               // Hh visible everywhere

    // ---- phase B: pair. s0/s1 alias As; w2s/sred alias Bs ----------------
    {
        unsigned short* s0  = As;                // 16KB
        unsigned short* s1  = As + 32 * 256;     // 16KB
        unsigned short* w2s = Bs;                // 512B
        float*          sred = (float*)(void*)(Bs + 256); // 1KB

        int bp = (b0 & 7) * 64 + (b0 >> 3);
        const int jt = bp & 3;  bp >>= 2;
        const int it = bp & 3;  bp >>= 2;
        const int n  = bp;

        const size_t base0 = ((size_t)(n * LL) + it * 32) * HH;
        const size_t base1 = ((size_t)(NUMB * LL + n * LL) + jt * 32) * HH;

        // async staging: wave w stages rows w*8..w*8+7 of both tiles.
        // LDS slot (row,pos) receives global h-unit f = pos ^ ((row>>2)&7).
        {
            const int pos = lane & 31, rhalf = lane >> 5;
#pragma unroll
            for (int i = 0; i < 4; ++i) {
                int rowbase = w * 8 + i * 2;
                int row = rowbase + rhalf;
                int f = pos ^ ((row >> 2) & 7);
                __builtin_amdgcn_global_load_lds(
                    (gas_t)(const void*)(Hh + base0 + (size_t)row * HH + f * 8),
                    (las_t)(void*)(s0 + rowbase * 256), 16, 0, 0);
                __builtin_amdgcn_global_load_lds(
                    (gas_t)(const void*)(Hh + base1 + (size_t)row * HH + f * 8),
                    (las_t)(void*)(s1 + rowbase * 256), 16, 0, 0);
            }
        }
        if (t < 64) {
            float4 v = *(const float4*)(W2 + t * 4);
            float2 pk;
            pk.x = pkh(v.x, v.y);
            pk.y = pkh(v.z, v.w);
            *(float2*)&w2s[t * 4] = pk;
        }
        __syncthreads();

        const int il = (t >> 3) & 7, jl = t & 7;
        float acc2[4][4] = {{0.f,0.f,0.f,0.f},{0.f,0.f,0.f,0.f},
                            {0.f,0.f,0.f,0.f},{0.f,0.f,0.f,0.f}};

#pragma unroll
        for (int f = 0; f < 8; ++f) {
            h16x8 wv = *(const h16x8*)&w2s[(w * 8 + f) * 8];   // wave-uniform
            const h16x2* wp = (const h16x2*)&wv;
            h16x8 av[4], bv[4];
#pragma unroll
            for (int r = 0; r < 4; ++r)
                av[r] = *(const h16x8*)&s0[(il * 4 + r) * 256 + (w * 8 + (f ^ il)) * 8];
#pragma unroll
            for (int s = 0; s < 4; ++s)
                bv[s] = *(const h16x8*)&s1[(jl * 4 + s) * 256 + (w * 8 + (f ^ jl)) * 8];
            const h16x8 zero = {0, 0, 0, 0, 0, 0, 0, 0};
#pragma unroll
            for (int r = 0; r < 4; ++r)
#pragma unroll
                for (int s = 0; s < 4; ++s) {
                    h16x8 sum = av[r] + bv[s];                  // v_pk_add_f16 x4
                    sum = __builtin_elementwise_max(sum, zero); // v_pk_max_f16 x4
                    const h16x2* sp = (const h16x2*)&sum;
#pragma unroll
                    for (int u = 0; u < 4; ++u)
                        acc2[r][s] = __builtin_amdgcn_fdot2(sp[u], wp[u], acc2[r][s], false);
                }
        }

        float total = 0.f;
#pragma unroll
        for (int r = 0; r < 4; ++r)
#pragma unroll
            for (int s = 0; s < 4; ++s) total += acc2[r][s];

        sred[t] = total;
        __syncthreads();

        if (t < 64) {
            float sum = sred[t] + sred[t + 64] + sred[t + 128] + sred[t + 192]
                      + 16.0f * b2[0];
            int i = it * 8 + (t >> 3);
            int j = jt * 8 + (t & 7);
            int p = n * 1024 + i * 32 + j;
            out[p] = sum;
            *(float2*)(out + NS + 2 * p) = make_float2((float)i, (float)j);
        }
    }
}

// ===========================================================================
// Fallback kernels (used only if cooperative launch is rejected).
// ===========================================================================
__global__ __launch_bounds__(256) void k_gemm(
    const float* __restrict__ fea,
    const int*   __restrict__ ind0,
    const int*   __restrict__ ind1,
    const float* __restrict__ b1,
    const unsigned short* __restrict__ WtP,
    unsigned short* __restrict__ Hh)
{
    __shared__ unsigned short As[64 * 256] __attribute__((aligned(16)));
    __shared__ unsigned short Bs[64 * 256] __attribute__((aligned(16)));

    const int b0 = blockIdx.x;
    const int b = (b0 & 7) * 64 + (b0 >> 3);
    const int ht = b & 3, rt = b >> 2;
    const int side = rt >> 6;
    const int R0 = rt * 64;
    const int t = threadIdx.x, w = t >> 6, lane = t & 63;

    const unsigned short* Wbase = WtP + ((size_t)(side * 4 + ht)) * 64 * 256;
#pragma unroll
    for (int i = 0; i < 8; ++i) {
        int chunk = w * 8 + i;
        __builtin_amdgcn_global_load_lds(
            (gas_t)(const void*)(Wbase + chunk * 512 + lane * 8),
            (las_t)(void*)(As + chunk * 512),
            16, 0, 0);
    }
    {
        const int lr = t >> 2;
        const int g = R0 + lr;
        const int rs = g & 4095, n_ = rs >> 7, a_ = rs & 127;
        const int id = (side ? ind1 : ind0)[n_ * LL + a_] + BAG * (a_ & 3);
        const float* arow = fea + (size_t)((n_ * 2 + side) * POOL + id) * DD;
        const int sw = lr & 7;
#pragma unroll
        for (int j0 = 0; j0 < 8; ++j0) {
            int u = j0 * 4 + (t & 3);
            float4 v0 = *(const float4*)(arow + u * 8);
            float4 v1 = *(const float4*)(arow + u * 8 + 4);
            unsigned int tmp[4] __attribute__((aligned(16)));
            tmp[0] = pkbf(v0.x, v0.y);
            tmp[1] = pkbf(v0.z, v0.w);
            tmp[2] = pkbf(v1.x, v1.y);
            tmp[3] = pkbf(v1.z, v1.w);
            int pos = u ^ sw;
            *(f32x4*)&Bs[lr * 256 + pos * 8] = *(const f32x4*)tmp;
        }
    }
    __syncthreads();

    const int l15 = lane & 15, q = lane >> 4;
    const int wh = w >> 1, wr = w & 1;
    f32x4 acc[2][2] = {};
#pragma unroll
    for (int kk = 0; kk < 8; ++kk) {
        const int u = kk * 4 + q;
        bf16x8 af[2], bfv[2];
#pragma unroll
        for (int a = 0; a < 2; ++a) {
            int hr = wh * 32 + a * 16 + l15;
            af[a] = *(const bf16x8*)&As[hr * 256 + (u ^ (hr & 7)) * 8];
        }
#pragma unroll
        for (int r = 0; r < 2; ++r) {
            int rr = wr * 32 + r * 16 + l15;
            bfv[r] = *(const bf16x8*)&Bs[rr * 256 + (u ^ (rr & 7)) * 8];
        }
#pragma unroll
        for (int a = 0; a < 2; ++a)
#pragma unroll
            for (int r = 0; r < 2; ++r)
                acc[a][r] = __builtin_amdgcn_mfma_f32_16x16x32_bf16(af[a], bfv[r], acc[a][r], 0, 0, 0);
    }

    const int hq = ht * 64 + wh * 32 + q * 4;
    float4 bias[2];
    bias[0] = make_float4(0.f, 0.f, 0.f, 0.f);
    bias[1] = bias[0];
    if (side == 0) {
        bias[0] = *(const float4*)(b1 + hq);
        bias[1] = *(const float4*)(b1 + hq + 16);
    }
#pragma unroll
    for (int a = 0; a < 2; ++a)
#pragma unroll
    for (int r = 0; r < 2; ++r) {
        int frow = R0 + wr * 32 + r * 16 + l15;
        float2 pk;
        pk.x = pkh(acc[a][r][0] + bias[a].x, acc[a][r][1] + bias[a].y);
        pk.y = pkh(acc[a][r][2] + bias[a].z, acc[a][r][3] + bias[a].w);
        *(float2*)&Hh[(size_t)frow * HH + hq + a * 16] = pk;
    }
}

__global__ __launch_bounds__(256) void k_pair(
    const unsigned short* __restrict__ Hh,
    const float* __restrict__ W2,
    const float* __restrict__ b2,
    float*       __restrict__ out)
{
    __shared__ unsigned short s0[32 * 256] __attribute__((aligned(16)));
    __shared__ unsigned short s1[32 * 256] __attribute__((aligned(16)));
    __shared__ unsigned short w2s[256]     __attribute__((aligned(16)));
    __shared__ float sred[256];

    const int b0 = blockIdx.x;
    int b = (b0 & 7) * 64 + (b0 >> 3);
    const int jt = b & 3;  b >>= 2;
    const int it = b & 3;  b >>= 2;
    const int n  = b;
    const int t = threadIdx.x, w = t >> 6, lane = t & 63;

    const size_t base0 = ((size_t)(n * LL) + it * 32) * HH;
    const size_t base1 = ((size_t)(NUMB * LL + n * LL) + jt * 32) * HH;

    {
        const int pos = lane & 31, rhalf = lane >> 5;
#pragma unroll
        for (int i = 0; i < 4; ++i) {
            int rowbase = w * 8 + i * 2;
            int row = rowbase + rhalf;
            int f = pos ^ ((row >> 2) & 7);
            __builtin_amdgcn_global_load_lds(
                (gas_t)(const void*)(Hh + base0 + (size_t)row * HH + f * 8),
                (las_t)(void*)(s0 + rowbase * 256), 16, 0, 0);
            __builtin_amdgcn_global_load_lds(
                (gas_t)(const void*)(Hh + base1 + (size_t)row * HH + f * 8),
                (las_t)(void*)(s1 + rowbase * 256), 16, 0, 0);
        }
    }
    if (t < 64) {
        float4 v = *(const float4*)(W2 + t * 4);
        float2 pk;
        pk.x = pkh(v.x, v.y);
        pk.y = pkh(v.z, v.w);
        *(float2*)&w2s[t * 4] = pk;
    }
    __syncthreads();

    const int il = (t >> 3) & 7, jl = t & 7;
    float acc[4][4] = {{0.f,0.f,0.f,0.f},{0.f,0.f,0.f,0.f},
                       {0.f,0.f,0.f,0.f},{0.f,0.f,0.f,0.f}};

#pragma unroll
    for (int f = 0; f < 8; ++f) {
        h16x8 wv = *(const h16x8*)&w2s[(w * 8 + f) * 8];
        const h16x2* wp = (const h16x2*)&wv;
        h16x8 av[4], bv[4];
#pragma unroll
        for (int r = 0; r < 4; ++r)
            av[r] = *(const h16x8*)&s0[(il * 4 + r) * 256 + (w * 8 + (f ^ il)) * 8];
#pragma unroll
        for (int s = 0; s < 4; ++s)
            bv[s] = *(const h16x8*)&s1[(jl * 4 + s) * 256 + (w * 8 + (f ^ jl)) * 8];
        const h16x8 zero = {0, 0, 0, 0, 0, 0, 0, 0};
#pragma unroll
        for (int r = 0; r < 4; ++r)
#pragma unroll
            for (int s = 0; s < 4; ++s) {
                h16x8 sum = av[r] + bv[s];
                sum = __builtin_elementwise_max(sum, zero);
                const h16x2* sp = (const h16x2*)&sum;
#pragma unroll
                for (int u = 0; u < 4; ++u)
                    acc[r][s] = __builtin_amdgcn_fdot2(sp[u], wp[u], acc[r][s], false);
            }
    }

    float total = 0.f;
#pragma unroll
    for (int r = 0; r < 4; ++r)
#pragma unroll
        for (int s = 0; s < 4; ++s) total += acc[r][s];

    sred[t] = total;
    __syncthreads();

    if (t < 64) {
        float sum = sred[t] + sred[t + 64] + sred[t + 128] + sred[t + 192]
                  + 16.0f * b2[0];
        int i = it * 8 + (t >> 3);
        int j = jt * 8 + (t & 7);
        int p = n * 1024 + i * 32 + j;
        out[p] = sum;
        *(float2*)(out + NS + 2 * p) = make_float2((float)i, (float)j);
    }
}

// ---------------------------------------------------------------------------
extern "C" void kernel_launch(void* const* d_in, const int* in_sizes, int n_in,
                              void* d_out, int out_size, void* d_ws, size_t ws_size,
                              hipStream_t stream)
{
    const float* fea  = (const float*)d_in[0];
    const int*   ind0 = (const int*)  d_in[1];
    const int*   ind1 = (const int*)  d_in[2];
    // d_in[3] = k (scalar 8, compile-time constant here)
    const float* W1a  = (const float*)d_in[4];
    const float* W1b  = (const float*)d_in[5];
    const float* b1   = (const float*)d_in[6];
    const float* W2   = (const float*)d_in[7];
    const float* b2   = (const float*)d_in[8];
    float* out = (float*)d_out;

    unsigned short* WtP = (unsigned short*)d_ws;                 // 256KB bf16 used
    unsigned*       cnt = (unsigned*)((char*)d_ws + 384 * 1024); // in WtP slot gap
    unsigned short* Hh  = (unsigned short*)((char*)d_ws + 512 * 1024); // 4MB fp16

    hipLaunchKernelGGL(k_prep, dim3(32), dim3(256), 0, stream,
                       W1a, W1b, WtP, cnt);

    void* kargs[] = {
        (void*)&fea, (void*)&ind0, (void*)&ind1, (void*)&b1,
        (void*)&W2,  (void*)&b2,  (void*)&WtP, (void*)&Hh,
        (void*)&out, (void*)&cnt
    };
    hipError_t e = hipLaunchCooperativeKernel(k_fused, dim3(512), dim3(256),
                                              kargs, 0u, stream);
    if (e != hipSuccess) {
        // Fallback: proven 3-kernel path (identical math).
        hipLaunchKernelGGL(k_gemm, dim3(512), dim3(256), 0, stream,
                           fea, ind0, ind1, b1, WtP, Hh);
        hipLaunchKernelGGL(k_pair, dim3(512), dim3(256), 0, stream,
                           Hh, W2, b2, out);
    }
}

// Round 4
// 128.376 us; speedup vs baseline: 2.0133x; 1.5546x over previous
//
#include <hip/hip_runtime.h>

// Problem constants (fixed by reference setup_inputs)
#define NUMB 32     // num
#define LL   128    // num_top*cobj
#define POOL 1200   // cobj*bag
#define BAG  300
#define DD   256    // feature dim
#define HH   256    // relation hidden
#define NS   (NUMB*32*32)   // 32768 scores

using bf16x8 = __bf16    __attribute__((ext_vector_type(8)));
using f32x4  = float     __attribute__((ext_vector_type(4)));
using fp16x2 = __fp16    __attribute__((ext_vector_type(2)));  // cvt_pkrtz result
using h16x2  = _Float16  __attribute__((ext_vector_type(2)));  // fdot2 operand
using h16x8  = _Float16  __attribute__((ext_vector_type(8)));

typedef const __attribute__((address_space(1))) unsigned int* gas_t;
typedef       __attribute__((address_space(3))) unsigned int* las_t;

static __device__ __forceinline__ unsigned short f2bf(float x) {
    unsigned u = __float_as_uint(x);
    return (unsigned short)((u + 0x7FFFu + ((u >> 16) & 1u)) >> 16);  // RNE
}

static __device__ __forceinline__ float pkh(float a, float b) {
    fp16x2 p = __builtin_amdgcn_cvt_pkrtz(a, b);
    return __builtin_bit_cast(float, p);
}

// pack two f32 -> two bf16 in one instr (lo = a, hi = b)
static __device__ __forceinline__ unsigned int pkbf(float a, float b) {
    unsigned int r;
    asm("v_cvt_pk_bf16_f32 %0, %1, %2" : "=v"(r) : "v"(a), "v"(b));
    return r;
}

// ---------------------------------------------------------------------------
// K0: W transpose+convert -> WtP bf16, pre-swizzled:
//     WtP[((side*4+ht)*64+nn)*32 + (U ^ (nn&7))] = Wt[h][k-unit U]
//     (unit = 8 bf16 = 16B; h = ht*64+nn; Wt[h][k] = W[k][h])
//     grid = 32 blocks (pairs init lives in k_pair epilogue).
//
// NOTE (R2/R3 lesson): do NOT fuse these three kernels with a grid-wide
// barrier. On MI355X any grid barrier (cg::sync or hand-rolled agent-scope
// atomic) costs ~50us at 512 blocks (cross-XCD L2 writeback serialization);
// kernel boundaries are the cheap synchronization here.
// ---------------------------------------------------------------------------
__global__ __launch_bounds__(256) void k_prep(
    const float* __restrict__ W1a, const float* __restrict__ W1b,
    unsigned short* __restrict__ WtP)
{
    const int blk = blockIdx.x, t = threadIdx.x;
    const int side = blk >> 4, kc = blk & 15;   // k-chunk of 16
    const float* W = side ? W1b : W1a;          // [k][h] row-major
    __shared__ float T[16][257];
    const int row = t >> 4, c = t & 15;
#pragma unroll
    for (int i = 0; i < 4; ++i) {
        int col4 = c + i * 16;
        float4 v = *(const float4*)(W + (size_t)(kc * 16 + row) * HH + col4 * 4);
        T[row][col4 * 4 + 0] = v.x; T[row][col4 * 4 + 1] = v.y;
        T[row][col4 * 4 + 2] = v.z; T[row][col4 * 4 + 3] = v.w;
    }
    __syncthreads();
    const int ht = t >> 6, nn = t & 63;
#pragma unroll
    for (int j = 0; j < 2; ++j) {
        unsigned short tmp[8] __attribute__((aligned(16)));
#pragma unroll
        for (int e = 0; e < 8; ++e) tmp[e] = f2bf(T[j * 8 + e][t]);
        int U = kc * 2 + j;
        int pos = U ^ (nn & 7);
        size_t unit = ((size_t)((side * 4 + ht) * 64 + nn)) * 32 + pos;
        *(float4*)(WtP + unit * 8) = *(float4*)tmp;
    }
}

// ---------------------------------------------------------------------------
// K1: gather + bf16 MFMA GEMM, computing H^T = Wt * F^T per tile.
//  Tile: M=64 h-rows (A = WtP quarter, via global_load_lds, pre-swizzled),
//        N=64 gathered feature rows (B, fp32->bf16 cvt_pk, swizzled ds_write),
//        K=256 fully staged. LDS = 32KB + 32KB. 256 thr, 1 barrier.
//  grid = rt(128) * ht(4) = 512, XCD-chunk swizzled so the 4 ht siblings of
//  one rt (same 64-row gather) land on one XCD's L2.
//  Wave tiling 2x2: wave (wh,wr) owns h-band wh*32 x row-band wr*32
//  -> 4 ds_read_b128 per 4 MFMA, block LDS traffic 128KB.
//  D layout (16x16x32): col = lane&15 = feature-row, row = quad*4+reg = h
//  -> 4 consecutive h per lane -> pack fp16 -> one 8B store into Hh[row][h].
// ---------------------------------------------------------------------------
__global__ __launch_bounds__(256) void k_gemm(
    const float* __restrict__ fea,
    const int*   __restrict__ ind0,
    const int*   __restrict__ ind1,
    const float* __restrict__ b1,
    const unsigned short* __restrict__ WtP,
    unsigned short* __restrict__ Hh)
{
    __shared__ unsigned short As[64 * 256] __attribute__((aligned(16))); // 32KB bf16
    __shared__ unsigned short Bs[64 * 256] __attribute__((aligned(16))); // 32KB bf16

    const int b0 = blockIdx.x;
    const int b = (b0 & 7) * 64 + (b0 >> 3);     // XCD-chunk swizzle (512 = 8*64)
    const int ht = b & 3, rt = b >> 2;
    const int side = rt >> 6;
    const int R0 = rt * 64;
    const int t = threadIdx.x, w = t >> 6, lane = t & 63;

    // --- A staging: async global->LDS, layout already swizzled in WtP ---
    const unsigned short* Wbase = WtP + ((size_t)(side * 4 + ht)) * 64 * 256;
#pragma unroll
    for (int i = 0; i < 8; ++i) {
        int chunk = w * 8 + i;               // 32 chunks of 1KB
        __builtin_amdgcn_global_load_lds(
            (gas_t)(const void*)(Wbase + chunk * 512 + lane * 8),
            (las_t)(void*)(As + chunk * 512),
            16, 0, 0);
    }

    // --- B staging: gather fp32 row, cvt_pk bf16, swizzled ds_write_b128 ---
    {
        const int lr = t >> 2;               // local row 0..63
        const int g = R0 + lr;
        const int rs = g & 4095, n_ = rs >> 7, a_ = rs & 127;
        const int id = (side ? ind1 : ind0)[n_ * LL + a_] + BAG * (a_ & 3);
        const float* arow = fea + (size_t)((n_ * 2 + side) * POOL + id) * DD;
        const int sw = lr & 7;
#pragma unroll
        for (int j0 = 0; j0 < 8; ++j0) {
            int u = j0 * 4 + (t & 3);        // 16B-unit 0..31
            float4 v0 = *(const float4*)(arow + u * 8);
            float4 v1 = *(const float4*)(arow + u * 8 + 4);
            unsigned int tmp[4] __attribute__((aligned(16)));
            tmp[0] = pkbf(v0.x, v0.y);
            tmp[1] = pkbf(v0.z, v0.w);
            tmp[2] = pkbf(v1.x, v1.y);
            tmp[3] = pkbf(v1.z, v1.w);
            int pos = u ^ sw;
            *(f32x4*)&Bs[lr * 256 + pos * 8] = *(const f32x4*)tmp;
        }
    }
    __syncthreads();   // drains global_load_lds (vmcnt) + ds_writes

    // --- K loop: 8 steps of K=32, pure LDS->MFMA, 2x2 wave tile ---
    const int l15 = lane & 15, q = lane >> 4;
    const int wh = w >> 1, wr = w & 1;
    f32x4 acc[2][2] = {};
#pragma unroll
    for (int kk = 0; kk < 8; ++kk) {
        const int u = kk * 4 + q;
        bf16x8 af[2], bfv[2];
#pragma unroll
        for (int a = 0; a < 2; ++a) {
            int hr = wh * 32 + a * 16 + l15;
            af[a] = *(const bf16x8*)&As[hr * 256 + (u ^ (hr & 7)) * 8];
        }
#pragma unroll
        for (int r = 0; r < 2; ++r) {
            int rr = wr * 32 + r * 16 + l15;
            bfv[r] = *(const bf16x8*)&Bs[rr * 256 + (u ^ (rr & 7)) * 8];
        }
#pragma unroll
        for (int a = 0; a < 2; ++a)
#pragma unroll
            for (int r = 0; r < 2; ++r)
                acc[a][r] = __builtin_amdgcn_mfma_f32_16x16x32_bf16(af[a], bfv[r], acc[a][r], 0, 0, 0);
    }

    // --- epilogue: +b1 (side 0), fp32 -> fp16, 8B stores into Hh[row][h] ---
    const int hq = ht * 64 + wh * 32 + q * 4;
    float4 bias[2];
    bias[0] = make_float4(0.f, 0.f, 0.f, 0.f);
    bias[1] = bias[0];
    if (side == 0) {
        bias[0] = *(const float4*)(b1 + hq);
        bias[1] = *(const float4*)(b1 + hq + 16);
    }
#pragma unroll
    for (int a = 0; a < 2; ++a)
#pragma unroll
    for (int r = 0; r < 2; ++r) {
        int frow = R0 + wr * 32 + r * 16 + l15;
        float2 pk;
        pk.x = pkh(acc[a][r][0] + bias[a].x, acc[a][r][1] + bias[a].y);
        pk.y = pkh(acc[a][r][2] + bias[a].z, acc[a][r][3] + bias[a].w);
        *(float2*)&Hh[(size_t)frow * HH + hq + a * 16] = pk;
    }
}

// ---------------------------------------------------------------------------
// K2: pairwise relu-reduce, fp16 packed + v_dot2_f32_f16 (fp32 accumulate).
//  grid = n(32) x it(4) x jt(4) = 512 blocks, XCD-chunk swizzled so the 16
//  blocks of one n (sharing Hh tiles) land on one XCD's L2.
//  Block covers 32 a-rows x 32 b-rows x ALL 256 h. Wave w = h-chunk w*64;
//  thread (hq=w, il, jl) does a 4x4 (a,b) patch over its 64 h; cross-hq merge
//  via LDS reduction; final store includes 16*b2 and writes the pairs entries
//  (no separate init pass).
//  LDS tiles fp16 [32 rows x 256 h], 16B-unit swizzle pos = u ^ ((row>>2)&7)
//  folded into the global_load_lds source address; read patterns (rows
//  il*4+r, stride-4) land on 8 distinct 16B-columns -> conflict-free.
// ---------------------------------------------------------------------------
__global__ __launch_bounds__(256) void k_pair(
    const unsigned short* __restrict__ Hh,
    const float* __restrict__ W2,
    const float* __restrict__ b2,
    float*       __restrict__ out)
{
    __shared__ unsigned short s0[32 * 256] __attribute__((aligned(16))); // 16KB fp16
    __shared__ unsigned short s1[32 * 256] __attribute__((aligned(16))); // 16KB fp16
    __shared__ unsigned short w2s[256]     __attribute__((aligned(16)));
    __shared__ float sred[256];

    const int b0 = blockIdx.x;
    int b = (b0 & 7) * 64 + (b0 >> 3);           // XCD-chunk swizzle (512 = 8*64)
    const int jt = b & 3;  b >>= 2;
    const int it = b & 3;  b >>= 2;
    const int n  = b;
    const int t = threadIdx.x, w = t >> 6, lane = t & 63;

    const size_t base0 = ((size_t)(n * LL) + it * 32) * HH;
    const size_t base1 = ((size_t)(NUMB * LL + n * LL) + jt * 32) * HH;

    // async staging: wave w stages rows w*8..w*8+7 of both tiles.
    // Each issue covers 2 rows (64 lanes x 16B = 1KB); LDS slot (row,pos)
    // receives global h-unit f = pos ^ ((row>>2)&7).
    {
        const int pos = lane & 31, rhalf = lane >> 5;
#pragma unroll
        for (int i = 0; i < 4; ++i) {
            int rowbase = w * 8 + i * 2;
            int row = rowbase + rhalf;
            int f = pos ^ ((row >> 2) & 7);
            __builtin_amdgcn_global_load_lds(
                (gas_t)(const void*)(Hh + base0 + (size_t)row * HH + f * 8),
                (las_t)(void*)(s0 + rowbase * 256), 16, 0, 0);
            __builtin_amdgcn_global_load_lds(
                (gas_t)(const void*)(Hh + base1 + (size_t)row * HH + f * 8),
                (las_t)(void*)(s1 + rowbase * 256), 16, 0, 0);
        }
    }
    if (t < 64) {
        float4 v = *(const float4*)(W2 + t * 4);
        float2 pk;
        pk.x = pkh(v.x, v.y);
        pk.y = pkh(v.z, v.w);
        *(float2*)&w2s[t * 4] = pk;
    }
    __syncthreads();

    const int il = (t >> 3) & 7, jl = t & 7;
    float acc[4][4] = {{0.f,0.f,0.f,0.f},{0.f,0.f,0.f,0.f},
                       {0.f,0.f,0.f,0.f},{0.f,0.f,0.f,0.f}};

#pragma unroll
    for (int f = 0; f < 8; ++f) {
        h16x8 wv = *(const h16x8*)&w2s[(w * 8 + f) * 8];   // wave-uniform
        const h16x2* wp = (const h16x2*)&wv;
        h16x8 av[4], bv[4];
#pragma unroll
        for (int r = 0; r < 4; ++r)
            av[r] = *(const h16x8*)&s0[(il * 4 + r) * 256 + (w * 8 + (f ^ il)) * 8];
#pragma unroll
        for (int s = 0; s < 4; ++s)
            bv[s] = *(const h16x8*)&s1[(jl * 4 + s) * 256 + (w * 8 + (f ^ jl)) * 8];
        const h16x8 zero = {0, 0, 0, 0, 0, 0, 0, 0};
#pragma unroll
        for (int r = 0; r < 4; ++r)
#pragma unroll
            for (int s = 0; s < 4; ++s) {
                h16x8 sum = av[r] + bv[s];                  // v_pk_add_f16 x4
                sum = __builtin_elementwise_max(sum, zero); // v_pk_max_f16 x4
                const h16x2* sp = (const h16x2*)&sum;
#pragma unroll
                for (int u = 0; u < 4; ++u)
                    acc[r][s] = __builtin_amdgcn_fdot2(sp[u], wp[u], acc[r][s], false);
            }
    }

    float total = 0.f;
#pragma unroll
    for (int r = 0; r < 4; ++r)
#pragma unroll
        for (int s = 0; s < 4; ++s) total += acc[r][s];

    sred[t] = total;
    __syncthreads();

    if (t < 64) {
        float sum = sred[t] + sred[t + 64] + sred[t + 128] + sred[t + 192]
                  + 16.0f * b2[0];
        int i = it * 8 + (t >> 3);
        int j = jt * 8 + (t & 7);
        int p = n * 1024 + i * 32 + j;
        out[p] = sum;
        // pairs entry (no separate init pass)
        *(float2*)(out + NS + 2 * p) = make_float2((float)i, (float)j);
    }
}

// ---------------------------------------------------------------------------
extern "C" void kernel_launch(void* const* d_in, const int* in_sizes, int n_in,
                              void* d_out, int out_size, void* d_ws, size_t ws_size,
                              hipStream_t stream)
{
    const float* fea  = (const float*)d_in[0];
    const int*   ind0 = (const int*)  d_in[1];
    const int*   ind1 = (const int*)  d_in[2];
    // d_in[3] = k (scalar 8, compile-time constant here)
    const float* W1a  = (const float*)d_in[4];
    const float* W1b  = (const float*)d_in[5];
    const float* b1   = (const float*)d_in[6];
    const float* W2   = (const float*)d_in[7];
    const float* b2   = (const float*)d_in[8];
    float* out = (float*)d_out;

    unsigned short* WtP = (unsigned short*)d_ws;                 // 256KB bf16
    unsigned short* Hh  = (unsigned short*)((char*)d_ws + 512 * 1024); // 4MB fp16

    hipLaunchKernelGGL(k_prep, dim3(32), dim3(256), 0, stream,
                       W1a, W1b, WtP);
    hipLaunchKernelGGL(k_gemm, dim3(512), dim3(256), 0, stream,
                       fea, ind0, ind1, b1, WtP, Hh);
    hipLaunchKernelGGL(k_pair, dim3(512), dim3(256), 0, stream,
                       Hh, W2, b2, out);
}